// Round 4
// baseline (52.948 us; speedup 1.0000x reference)
//
#include <hip/hip_runtime.h>

typedef float v2f __attribute__((ext_vector_type(2)));
typedef float v4f __attribute__((ext_vector_type(4)));

#define TILE 256        // j's staged per block; also block size
#define G_CONST 0.001f
#define EPS_CONST 1e-6f

// Grid: (N/TILE i-tiles, N/TILE j-tiles, B) = 16x16x8 = 2048 blocks of 256.
// 8 blocks/CU -> 32 waves/CU (8/SIMD) for latency hiding; body kept lean to
// fit <=64 VGPR (occupancy cliff at 65).
__global__ __launch_bounds__(256, 8)
void grav_kernel(const float* __restrict__ q, const float* __restrict__ m,
                 float* __restrict__ out, int N) {
  const int b   = blockIdx.z;
  const int tid = threadIdx.x;
  const int j0  = blockIdx.y * TILE;
  const int i   = blockIdx.x * TILE + tid;

  __shared__ float xs[TILE], ys[TILE], zs[TILE], ms[TILE];
  __shared__ float wsum[4];

  const float* qb = q + (size_t)b * N * 3;

  // Stage j tile (SoA -> broadcast ds_read_b128 in the inner loop).
  {
    const int j = j0 + tid;
    xs[tid] = qb[3 * j + 0];
    ys[tid] = qb[3 * j + 1];
    zs[tid] = qb[3 * j + 2];
    ms[tid] = m[j];
  }

  const float xi = qb[3 * i + 0];
  const float yi = qb[3 * i + 1];
  const float zi = qb[3 * i + 2];
  const float mi = m[i];
  const v2f xi2 = {xi, xi}, yi2 = {yi, yi}, zi2 = {zi, zi};
  const v2f eps2 = {EPS_CONST, EPS_CONST};

  __syncthreads();

  // Two independent v2f chains per 4-j group: 8+ indep dep-chains in flight.
  v2f acc0 = {0.f, 0.f}, acc1 = {0.f, 0.f};
  for (int k = 0; k < TILE; k += 4) {
    const v4f jx = *(const v4f*)&xs[k];   // uniform addr -> HW broadcast
    const v4f jy = *(const v4f*)&ys[k];
    const v4f jz = *(const v4f*)&zs[k];
    const v4f jm = *(const v4f*)&ms[k];

    const v2f jx0 = {jx.x, jx.y}, jx1 = {jx.z, jx.w};
    const v2f jy0 = {jy.x, jy.y}, jy1 = {jy.z, jy.w};
    const v2f jz0 = {jz.x, jz.y}, jz1 = {jz.z, jz.w};
    const v2f jm0 = {jm.x, jm.y}, jm1 = {jm.z, jm.w};

    const v2f dx0 = jx0 - xi2, dy0 = jy0 - yi2, dz0 = jz0 - zi2;
    const v2f dx1 = jx1 - xi2, dy1 = jy1 - yi2, dz1 = jz1 - zi2;

    v2f r0 = __builtin_elementwise_fma(dz0, dz0, eps2);
    v2f r1 = __builtin_elementwise_fma(dz1, dz1, eps2);
    r0 = __builtin_elementwise_fma(dy0, dy0, r0);
    r1 = __builtin_elementwise_fma(dy1, dy1, r1);
    r0 = __builtin_elementwise_fma(dx0, dx0, r0);
    r1 = __builtin_elementwise_fma(dx1, dx1, r1);

    const v2f ri0 = {__builtin_amdgcn_rsqf(r0.x), __builtin_amdgcn_rsqf(r0.y)};
    const v2f ri1 = {__builtin_amdgcn_rsqf(r1.x), __builtin_amdgcn_rsqf(r1.y)};

    acc0 = __builtin_elementwise_fma(jm0, ri0, acc0);
    acc1 = __builtin_elementwise_fma(jm1, ri1, acc1);
  }

  // Self-term cancels bit-exactly: at i==j the loop computed r2 == EPS via the
  // same fma chain, contributing mi * rsqf(EPS); subtract the identical value.
  float h = (acc0.x + acc0.y) + (acc1.x + acc1.y);
  if (i >= j0 && i < j0 + TILE) h -= mi * __builtin_amdgcn_rsqf(EPS_CONST);
  float tsum = mi * h;

  // Block reduction: 64-lane shuffle, then across 4 waves via LDS.
#pragma unroll
  for (int off = 32; off > 0; off >>= 1) tsum += __shfl_down(tsum, off);
  const int wid  = tid >> 6;
  const int lane = tid & 63;
  if (lane == 0) wsum[wid] = tsum;
  __syncthreads();
  if (tid == 0) {
    const float s = (wsum[0] + wsum[1]) + (wsum[2] + wsum[3]);
    atomicAdd(out + b, s * (-0.5f * G_CONST));
  }
}

extern "C" void kernel_launch(void* const* d_in, const int* in_sizes, int n_in,
                              void* d_out, int out_size, void* d_ws, size_t ws_size,
                              hipStream_t stream) {
  const float* q = (const float*)d_in[0];
  const float* m = (const float*)d_in[1];
  float* out = (float*)d_out;

  const int N = in_sizes[1];
  const int B = in_sizes[0] / (N * 3);

  hipMemsetAsync(out, 0, (size_t)out_size * sizeof(float), stream);

  dim3 grid(N / TILE, N / TILE, B);   // 16 x 16 x 8 = 2048 blocks
  grav_kernel<<<grid, TILE, 0, stream>>>(q, m, out, N);
}

// Round 5
// 35.189 us; speedup vs baseline: 1.5047x; 1.5047x over previous
//
#include <hip/hip_runtime.h>

typedef float v2f __attribute__((ext_vector_type(2)));
typedef float v4f __attribute__((ext_vector_type(4)));

#define BLK 256
#define IPT 8                 // i-particles per thread (LDS bytes/pair = 16/IPT)
#define TI (BLK * IPT)        // 2048 i's per block
#define TJ 64                 // j's staged per block
#define G_CONST 0.001f
#define EPS_CONST 1e-6f

// Grid: (N/TI=2, N/TJ=64, B=8) = 1024 blocks of 256 -> 4 blocks/CU, 16 waves/CU.
// Each ds_read_b128 of j-data is reused across IPT=8 i-slots: LDS traffic drops
// from 16 B/pair (R4, ~31us LDS-BW floor) to 2 B/pair (~5us, hidden).
__global__ __launch_bounds__(BLK, 4)
void grav_kernel(const float* __restrict__ q, const float* __restrict__ m,
                 float* __restrict__ out, int N) {
  const int b   = blockIdx.z;
  const int tid = threadIdx.x;
  const int j0  = blockIdx.y * TJ;
  const int i0  = blockIdx.x * TI;

  __shared__ float xs[TJ], ys[TJ], zs[TJ], ms[TJ];
  __shared__ float wsum[4];

  const float* qb = q + (size_t)b * N * 3;

  // Stage j tile (SoA -> broadcast ds_read_b128 in the inner loop).
  if (tid < TJ) {
    const int j = j0 + tid;
    xs[tid] = qb[3 * j + 0];
    ys[tid] = qb[3 * j + 1];
    zs[tid] = qb[3 * j + 2];
    ms[tid] = m[j];
  }

  // 8 i-slots per thread, coords splatted to v2f (loop-invariant registers).
  v2f xi2[IPT], yi2[IPT], zi2[IPT];
  float mi[IPT];
#pragma unroll
  for (int s = 0; s < IPT; ++s) {
    const int i = i0 + s * BLK + tid;
    const float x = qb[3 * i + 0];
    const float y = qb[3 * i + 1];
    const float z = qb[3 * i + 2];
    xi2[s] = (v2f){x, x};
    yi2[s] = (v2f){y, y};
    zi2[s] = (v2f){z, z};
    mi[s]  = m[i];
  }

  __syncthreads();

  const v2f eps2 = {EPS_CONST, EPS_CONST};
  v2f acc[IPT] = {};   // one accumulator per slot (keeps VGPR <= 128)

  for (int k = 0; k < TJ; k += 4) {
    const v4f jx = *(const v4f*)&xs[k];   // uniform addr -> broadcast read
    const v4f jy = *(const v4f*)&ys[k];
    const v4f jz = *(const v4f*)&zs[k];
    const v4f jm = *(const v4f*)&ms[k];
    const v2f jx0 = {jx.x, jx.y}, jx1 = {jx.z, jx.w};
    const v2f jy0 = {jy.x, jy.y}, jy1 = {jy.z, jy.w};
    const v2f jz0 = {jz.x, jz.y}, jz1 = {jz.z, jz.w};
    const v2f jm0 = {jm.x, jm.y}, jm1 = {jm.z, jm.w};

#pragma unroll
    for (int s = 0; s < IPT; ++s) {
      const v2f dx0 = jx0 - xi2[s], dy0 = jy0 - yi2[s], dz0 = jz0 - zi2[s];
      const v2f dx1 = jx1 - xi2[s], dy1 = jy1 - yi2[s], dz1 = jz1 - zi2[s];

      v2f r0 = __builtin_elementwise_fma(dz0, dz0, eps2);
      v2f r1 = __builtin_elementwise_fma(dz1, dz1, eps2);
      r0 = __builtin_elementwise_fma(dy0, dy0, r0);
      r1 = __builtin_elementwise_fma(dy1, dy1, r1);
      r0 = __builtin_elementwise_fma(dx0, dx0, r0);
      r1 = __builtin_elementwise_fma(dx1, dx1, r1);

      const v2f ri0 = {__builtin_amdgcn_rsqf(r0.x), __builtin_amdgcn_rsqf(r0.y)};
      const v2f ri1 = {__builtin_amdgcn_rsqf(r1.x), __builtin_amdgcn_rsqf(r1.y)};

      acc[s] = __builtin_elementwise_fma(jm0, ri0, acc[s]);
      acc[s] = __builtin_elementwise_fma(jm1, ri1, acc[s]);
    }
  }

  // Self-term: at i==j the loop computed r2 == EPS exactly (pure fma chain on
  // identical loaded values), contributing mi*rsq(EPS); subtract that.
  float tsum = 0.f;
#pragma unroll
  for (int s = 0; s < IPT; ++s) {
    const int i = i0 + s * BLK + tid;
    float h = acc[s].x + acc[s].y;
    if (i >= j0 && i < j0 + TJ) h -= mi[s] * __builtin_amdgcn_rsqf(EPS_CONST);
    tsum += mi[s] * h;
  }

  // Block reduction: 64-lane shuffle, then across 4 waves via LDS.
#pragma unroll
  for (int off = 32; off > 0; off >>= 1) tsum += __shfl_down(tsum, off);
  const int wid  = tid >> 6;
  const int lane = tid & 63;
  if (lane == 0) wsum[wid] = tsum;
  __syncthreads();
  if (tid == 0) {
    const float s = (wsum[0] + wsum[1]) + (wsum[2] + wsum[3]);
    atomicAdd(out + b, s * (-0.5f * G_CONST));
  }
}

extern "C" void kernel_launch(void* const* d_in, const int* in_sizes, int n_in,
                              void* d_out, int out_size, void* d_ws, size_t ws_size,
                              hipStream_t stream) {
  const float* q = (const float*)d_in[0];
  const float* m = (const float*)d_in[1];
  float* out = (float*)d_out;

  const int N = in_sizes[1];
  const int B = in_sizes[0] / (N * 3);

  hipMemsetAsync(out, 0, (size_t)out_size * sizeof(float), stream);

  dim3 grid(N / TI, N / TJ, B);   // 2 x 64 x 8 = 1024 blocks
  grav_kernel<<<grid, BLK, 0, stream>>>(q, m, out, N);
}